// Round 14
// baseline (60.997 us; speedup 1.0000x reference)
//
#include <hip/hip_runtime.h>
#include <hip/hip_fp16.h>
#include <cmath>

// SSIM fused kernel v14 = v13 (column-parallel phase 2, 59.1 us) + LDS
// capacity cut for 5 blocks/CU (was 4):
// - mu plane packed __half2 (f16 mu passed in v9/v11; only f16 ms/mx ever
//   failed). Phase-2: 1 ds_read_b32 + 2 cvt per tap.
// - (ms,mx) interleaved float2 -> 1 ds_read_b64 per tap (contiguous 8B/lane).
// - LDS 28416 B = 74*32*(4+8); phase-2 LDS instrs 72 -> 36 per thread.
// Keeps: column-parallel phase 2 (1 col x 8 rows, 18-row sliding window),
// natural-order phase 1, rcpf, parallel 2-stage tail, NO launch_bounds 2nd arg.

#define W 512
#define H 512
#define OWD 502
#define OHD 502
#define TILEC 32
#define TILER 64
#define INR 74            // halo'd rows
#define NVALID 12096192   // 48 * 502 * 502
#define NBLKX 16
#define NBLKY 8
#define NPART (NBLKX * NBLKY * 48 * 4)   // 24576 = one partial per wave
#define NRB 24                            // reduce1 blocks (24*1024 = NPART)

struct Weights { float g[11]; };
struct H2x4 { __half2 h[4]; };

__global__ __launch_bounds__(256) void ssim_kernel(
    const float* __restrict__ x, const float* __restrict__ y,
    float* __restrict__ partial, float* __restrict__ accum, int use_atomic, Weights wt)
{
    __shared__ __align__(16) __half2 hA[INR][TILEC];   // (mu1,mu2)  9472 B
    __shared__ __align__(16) float2  hB[INR][TILEC];   // (ms,mx)   18944 B

    const int tid = threadIdx.x;
    const int r0 = blockIdx.y * TILER;
    const int c0 = blockIdx.x * TILEC;
    const size_t plane = (size_t)blockIdx.z * (W * H);
    const float* xp = x + plane;
    const float* yp = y + plane;

    // ---- Phase 1: horizontal pass over 74 rows x 8 col-groups (natural order).
    for (int i = tid; i < INR * 8; i += 256) {
        const int p = i >> 3;                 // row 0..73
        const int cg = (i & 7) << 2;          // col group offset 0..28
        const int gr = r0 + p;
        float xv[16], yv[16];
        if (gr < H) {
            const float* xr = xp + (size_t)gr * W;
            const float* yr = yp + (size_t)gr * W;
            #pragma unroll
            for (int q = 0; q < 4; q++) {
                const int gc = c0 + cg + 4 * q;
                float4 a = make_float4(0.f, 0.f, 0.f, 0.f);
                float4 b = make_float4(0.f, 0.f, 0.f, 0.f);
                if (gc < W) {  // W%4==0, gc%4==0 -> float4 fully in or out
                    a = *(const float4*)(xr + gc);
                    b = *(const float4*)(yr + gc);
                }
                xv[4*q+0] = a.x; xv[4*q+1] = a.y; xv[4*q+2] = a.z; xv[4*q+3] = a.w;
                yv[4*q+0] = b.x; yv[4*q+1] = b.y; yv[4*q+2] = b.z; yv[4*q+3] = b.w;
            }
        } else {
            #pragma unroll
            for (int j = 0; j < 16; j++) { xv[j] = 0.f; yv[j] = 0.f; }
        }
        // Hoisted products: ss = x^2 + y^2 (one plane), xy.
        float ssv[16], xyv[16];
        #pragma unroll
        for (int j = 0; j < 16; j++) {
            ssv[j] = xv[j] * xv[j] + yv[j] * yv[j];
            xyv[j] = xv[j] * yv[j];
        }
        float m1[4]  = {0.f, 0.f, 0.f, 0.f};
        float m2[4]  = {0.f, 0.f, 0.f, 0.f};
        float ms[4]  = {0.f, 0.f, 0.f, 0.f};
        float mx[4]  = {0.f, 0.f, 0.f, 0.f};
        #pragma unroll
        for (int k2 = 0; k2 < 11; k2++) {
            const float w = wt.g[k2];
            #pragma unroll
            for (int j = 0; j < 4; j++) {
                m1[j] += w * xv[j + k2];
                m2[j] += w * yv[j + k2];
                ms[j] += w * ssv[j + k2];
                mx[j] += w * xyv[j + k2];
            }
        }
        // mu plane: pack f16x2, one b128 store for 4 cols.
        H2x4 st;
        #pragma unroll
        for (int j = 0; j < 4; j++)
            st.h[j] = __halves2half2(__float2half(m1[j]), __float2half(m2[j]));
        *(H2x4*)&hA[p][cg] = st;
        // (ms,mx) plane: two b128 stores for 4 cols.
        *(float4*)&hB[p][cg]     = make_float4(ms[0], mx[0], ms[1], mx[1]);
        *(float4*)&hB[p][cg + 2] = make_float4(ms[2], mx[2], ms[3], mx[3]);
    }
    __syncthreads();

    // ---- Phase 2: column-parallel vertical pass + SSIM.
    // Thread = 1 col x 8 output rows; 18-row sliding window, scalar reads.
    float lsum = 0.f;
    {
        const int o8 = (tid >> 5) << 3;   // octet base row: 0,8,...,56
        const int col = tid & 31;

        float am1[8], am2[8], as2[8], ax2[8];
        #pragma unroll
        for (int r = 0; r < 8; r++) {
            am1[r] = 0.f; am2[r] = 0.f; as2[r] = 0.f; ax2[r] = 0.f;
        }

        #pragma unroll
        for (int t = 0; t < 18; t++) {
            const int row = o8 + t;
            const float2 f = __half22float2(hA[row][col]);   // (mu1, mu2)
            const float2 sx = hB[row][col];                   // (ms, mx)
            #pragma unroll
            for (int r = 0; r < 8; r++) {
                const int k = t - r;
                if (k >= 0 && k <= 10) {
                    const float w = wt.g[k];
                    am1[r] += w * f.x;
                    am2[r] += w * f.y;
                    as2[r] += w * sx.x;
                    ax2[r] += w * sx.y;
                }
            }
        }

        const float C1 = 1e-4f;   // (0.01*1)^2
        const float C2 = 9e-4f;   // (0.03*1)^2
        const int ocol = c0 + col;
        if (ocol < OWD) {
            #pragma unroll
            for (int r = 0; r < 8; r++) {
                const int orow = r0 + o8 + r;
                if (orow < OHD) {
                    const float mu1 = am1[r], mu2 = am2[r];
                    const float mu12 = mu1 * mu2;
                    const float mu1s = mu1 * mu1;
                    const float mu2s = mu2 * mu2;
                    const float sss = as2[r] - mu1s - mu2s;  // s11+s22
                    const float s12 = ax2[r] - mu12;
                    const float num = (2.f * mu12 + C1) * (2.f * s12 + C2);
                    const float den = (mu1s + mu2s + C1) * (sss + C2);
                    lsum += num * __builtin_amdgcn_rcpf(den);
                }
            }
        }
    }

    // ---- Per-wave reduction; one partial (or atomic) per wave.
    #pragma unroll
    for (int off = 32; off > 0; off >>= 1) lsum += __shfl_down(lsum, off, 64);
    if ((tid & 63) == 0) {
        const int wave = tid >> 6;
        const int bid = (blockIdx.z * NBLKY + blockIdx.y) * NBLKX + blockIdx.x;
        if (use_atomic) unsafeAtomicAdd(accum, lsum);
        else partial[bid * 4 + wave] = lsum;
    }
}

// Stage-1 reduce: 24 blocks x 1024 threads, each block sums a 1024-chunk.
__global__ __launch_bounds__(1024) void reduce1_kernel(
    const float* __restrict__ partial, float* __restrict__ bsum)
{
    __shared__ float ws[16];
    float s = partial[blockIdx.x * 1024 + threadIdx.x];
    #pragma unroll
    for (int off = 32; off > 0; off >>= 1) s += __shfl_down(s, off, 64);
    const int wave = threadIdx.x >> 6;
    if ((threadIdx.x & 63) == 0) ws[wave] = s;
    __syncthreads();
    if (threadIdx.x == 0) {
        float t = 0.f;
        #pragma unroll
        for (int i = 0; i < 16; i++) t += ws[i];
        bsum[blockIdx.x] = t;
    }
}

// Stage-2 reduce: one wave sums the 24 block sums and divides.
__global__ void reduce2_kernel(const float* __restrict__ bsum, float* __restrict__ out)
{
    float s = (threadIdx.x < NRB) ? bsum[threadIdx.x] : 0.f;
    #pragma unroll
    for (int off = 32; off > 0; off >>= 1) s += __shfl_down(s, off, 64);
    if (threadIdx.x == 0) out[0] = s * (1.0f / (float)NVALID);
}

__global__ void finalize_kernel(const float* __restrict__ accum, float* __restrict__ out) {
    out[0] = accum[0] * (1.0f / (float)NVALID);
}

extern "C" void kernel_launch(void* const* d_in, const int* in_sizes, int n_in,
                              void* d_out, int out_size, void* d_ws, size_t ws_size,
                              hipStream_t stream) {
    const float* x = (const float*)d_in[0];
    const float* y = (const float*)d_in[1];
    float* out = (float*)d_out;
    float* ws = (float*)d_ws;

    // Gaussian window, computed in double like the numpy reference, cast to f32.
    Weights wt;
    {
        double g[11], s = 0.0;
        for (int i = 0; i < 11; i++) {
            double d = (double)(i - 5);
            g[i] = exp(-(d * d) / (2.0 * 1.5 * 1.5));
            s += g[i];
        }
        for (int i = 0; i < 11; i++) wt.g[i] = (float)(g[i] / s);
    }

    dim3 grid(NBLKX, NBLKY, 48);
    const size_t need = (size_t)(NPART + NRB) * sizeof(float);
    const int use_atomic = (ws_size < need) ? 1 : 0;
    if (use_atomic) {
        hipMemsetAsync(ws, 0, sizeof(float), stream);
        ssim_kernel<<<grid, 256, 0, stream>>>(x, y, ws, ws, 1, wt);
        finalize_kernel<<<1, 1, 0, stream>>>(ws, out);
    } else {
        float* bsum = ws + NPART;
        ssim_kernel<<<grid, 256, 0, stream>>>(x, y, ws, ws, 0, wt);
        reduce1_kernel<<<NRB, 1024, 0, stream>>>(ws, bsum);
        reduce2_kernel<<<1, 64, 0, stream>>>(bsum, out);
    }
}

// Round 15
// 59.121 us; speedup vs baseline: 1.0317x; 1.0317x over previous
//
#include <hip/hip_runtime.h>
#include <hip/hip_fp16.h>
#include <cmath>

// SSIM fused kernel v15 = v13 column-parallel phase 2 + v14's LDS capacity,
// minus v14's bank conflict:
// - mu plane packed __half2 (accuracy-proven v9/v11/v14): 9472 B.
// - ms, mx as SEPARATE f32 scalar planes (v13's perfect bank pattern:
//   32 lanes x 4B consecutive; b64-interleaved in v14 hit even banks only
//   -> 909K conflict cycles). 2 x 9472 B.
// - LDS 28416 B -> 5 blocks/CU (v13's 37888 allowed only 4).
// - Phase 2: 3 scalar ds_read_b32 per tap (54/thread), conflict-free.
// Keeps: natural-order phase 1, rcpf, parallel 2-stage tail,
// NO launch_bounds 2nd arg (burned twice).

#define W 512
#define H 512
#define OWD 502
#define OHD 502
#define TILEC 32
#define TILER 64
#define INR 74            // halo'd rows
#define NVALID 12096192   // 48 * 502 * 502
#define NBLKX 16
#define NBLKY 8
#define NPART (NBLKX * NBLKY * 48 * 4)   // 24576 = one partial per wave
#define NRB 24                            // reduce1 blocks (24*1024 = NPART)

struct Weights { float g[11]; };
struct H2x4 { __half2 h[4]; };

__global__ __launch_bounds__(256) void ssim_kernel(
    const float* __restrict__ x, const float* __restrict__ y,
    float* __restrict__ partial, float* __restrict__ accum, int use_atomic, Weights wt)
{
    __shared__ __align__(16) __half2 hA[INR][TILEC];   // (mu1,mu2) 9472 B
    __shared__ __align__(16) float   hms[INR][TILEC];  // ms        9472 B
    __shared__ __align__(16) float   hmx[INR][TILEC];  // mx        9472 B

    const int tid = threadIdx.x;
    const int r0 = blockIdx.y * TILER;
    const int c0 = blockIdx.x * TILEC;
    const size_t plane = (size_t)blockIdx.z * (W * H);
    const float* xp = x + plane;
    const float* yp = y + plane;

    // ---- Phase 1: horizontal pass over 74 rows x 8 col-groups (natural order).
    for (int i = tid; i < INR * 8; i += 256) {
        const int p = i >> 3;                 // row 0..73
        const int cg = (i & 7) << 2;          // col group offset 0..28
        const int gr = r0 + p;
        float xv[16], yv[16];
        if (gr < H) {
            const float* xr = xp + (size_t)gr * W;
            const float* yr = yp + (size_t)gr * W;
            #pragma unroll
            for (int q = 0; q < 4; q++) {
                const int gc = c0 + cg + 4 * q;
                float4 a = make_float4(0.f, 0.f, 0.f, 0.f);
                float4 b = make_float4(0.f, 0.f, 0.f, 0.f);
                if (gc < W) {  // W%4==0, gc%4==0 -> float4 fully in or out
                    a = *(const float4*)(xr + gc);
                    b = *(const float4*)(yr + gc);
                }
                xv[4*q+0] = a.x; xv[4*q+1] = a.y; xv[4*q+2] = a.z; xv[4*q+3] = a.w;
                yv[4*q+0] = b.x; yv[4*q+1] = b.y; yv[4*q+2] = b.z; yv[4*q+3] = b.w;
            }
        } else {
            #pragma unroll
            for (int j = 0; j < 16; j++) { xv[j] = 0.f; yv[j] = 0.f; }
        }
        // Hoisted products: ss = x^2 + y^2 (one plane), xy.
        float ssv[16], xyv[16];
        #pragma unroll
        for (int j = 0; j < 16; j++) {
            ssv[j] = xv[j] * xv[j] + yv[j] * yv[j];
            xyv[j] = xv[j] * yv[j];
        }
        float m1[4]  = {0.f, 0.f, 0.f, 0.f};
        float m2[4]  = {0.f, 0.f, 0.f, 0.f};
        float ms[4]  = {0.f, 0.f, 0.f, 0.f};
        float mx[4]  = {0.f, 0.f, 0.f, 0.f};
        #pragma unroll
        for (int k2 = 0; k2 < 11; k2++) {
            const float w = wt.g[k2];
            #pragma unroll
            for (int j = 0; j < 4; j++) {
                m1[j] += w * xv[j + k2];
                m2[j] += w * yv[j + k2];
                ms[j] += w * ssv[j + k2];
                mx[j] += w * xyv[j + k2];
            }
        }
        // mu plane: pack f16x2, one b128 store for 4 cols.
        H2x4 st;
        #pragma unroll
        for (int j = 0; j < 4; j++)
            st.h[j] = __halves2half2(__float2half(m1[j]), __float2half(m2[j]));
        *(H2x4*)&hA[p][cg] = st;
        *(float4*)&hms[p][cg] = make_float4(ms[0], ms[1], ms[2], ms[3]);
        *(float4*)&hmx[p][cg] = make_float4(mx[0], mx[1], mx[2], mx[3]);
    }
    __syncthreads();

    // ---- Phase 2: column-parallel vertical pass + SSIM.
    // Thread = 1 col x 8 output rows; 18-row sliding window, scalar reads.
    float lsum = 0.f;
    {
        const int o8 = (tid >> 5) << 3;   // octet base row: 0,8,...,56
        const int col = tid & 31;

        float am1[8], am2[8], as2[8], ax2[8];
        #pragma unroll
        for (int r = 0; r < 8; r++) {
            am1[r] = 0.f; am2[r] = 0.f; as2[r] = 0.f; ax2[r] = 0.f;
        }

        #pragma unroll
        for (int t = 0; t < 18; t++) {
            const int row = o8 + t;
            const float2 f = __half22float2(hA[row][col]);   // (mu1, mu2)
            const float ms = hms[row][col];
            const float mx = hmx[row][col];
            #pragma unroll
            for (int r = 0; r < 8; r++) {
                const int k = t - r;
                if (k >= 0 && k <= 10) {
                    const float w = wt.g[k];
                    am1[r] += w * f.x;
                    am2[r] += w * f.y;
                    as2[r] += w * ms;
                    ax2[r] += w * mx;
                }
            }
        }

        const float C1 = 1e-4f;   // (0.01*1)^2
        const float C2 = 9e-4f;   // (0.03*1)^2
        const int ocol = c0 + col;
        if (ocol < OWD) {
            #pragma unroll
            for (int r = 0; r < 8; r++) {
                const int orow = r0 + o8 + r;
                if (orow < OHD) {
                    const float mu1 = am1[r], mu2 = am2[r];
                    const float mu12 = mu1 * mu2;
                    const float mu1s = mu1 * mu1;
                    const float mu2s = mu2 * mu2;
                    const float sss = as2[r] - mu1s - mu2s;  // s11+s22
                    const float s12 = ax2[r] - mu12;
                    const float num = (2.f * mu12 + C1) * (2.f * s12 + C2);
                    const float den = (mu1s + mu2s + C1) * (sss + C2);
                    lsum += num * __builtin_amdgcn_rcpf(den);
                }
            }
        }
    }

    // ---- Per-wave reduction; one partial (or atomic) per wave.
    #pragma unroll
    for (int off = 32; off > 0; off >>= 1) lsum += __shfl_down(lsum, off, 64);
    if ((tid & 63) == 0) {
        const int wave = tid >> 6;
        const int bid = (blockIdx.z * NBLKY + blockIdx.y) * NBLKX + blockIdx.x;
        if (use_atomic) unsafeAtomicAdd(accum, lsum);
        else partial[bid * 4 + wave] = lsum;
    }
}

// Stage-1 reduce: 24 blocks x 1024 threads, each block sums a 1024-chunk.
__global__ __launch_bounds__(1024) void reduce1_kernel(
    const float* __restrict__ partial, float* __restrict__ bsum)
{
    __shared__ float ws[16];
    float s = partial[blockIdx.x * 1024 + threadIdx.x];
    #pragma unroll
    for (int off = 32; off > 0; off >>= 1) s += __shfl_down(s, off, 64);
    const int wave = threadIdx.x >> 6;
    if ((threadIdx.x & 63) == 0) ws[wave] = s;
    __syncthreads();
    if (threadIdx.x == 0) {
        float t = 0.f;
        #pragma unroll
        for (int i = 0; i < 16; i++) t += ws[i];
        bsum[blockIdx.x] = t;
    }
}

// Stage-2 reduce: one wave sums the 24 block sums and divides.
__global__ void reduce2_kernel(const float* __restrict__ bsum, float* __restrict__ out)
{
    float s = (threadIdx.x < NRB) ? bsum[threadIdx.x] : 0.f;
    #pragma unroll
    for (int off = 32; off > 0; off >>= 1) s += __shfl_down(s, off, 64);
    if (threadIdx.x == 0) out[0] = s * (1.0f / (float)NVALID);
}

__global__ void finalize_kernel(const float* __restrict__ accum, float* __restrict__ out) {
    out[0] = accum[0] * (1.0f / (float)NVALID);
}

extern "C" void kernel_launch(void* const* d_in, const int* in_sizes, int n_in,
                              void* d_out, int out_size, void* d_ws, size_t ws_size,
                              hipStream_t stream) {
    const float* x = (const float*)d_in[0];
    const float* y = (const float*)d_in[1];
    float* out = (float*)d_out;
    float* ws = (float*)d_ws;

    // Gaussian window, computed in double like the numpy reference, cast to f32.
    Weights wt;
    {
        double g[11], s = 0.0;
        for (int i = 0; i < 11; i++) {
            double d = (double)(i - 5);
            g[i] = exp(-(d * d) / (2.0 * 1.5 * 1.5));
            s += g[i];
        }
        for (int i = 0; i < 11; i++) wt.g[i] = (float)(g[i] / s);
    }

    dim3 grid(NBLKX, NBLKY, 48);
    const size_t need = (size_t)(NPART + NRB) * sizeof(float);
    const int use_atomic = (ws_size < need) ? 1 : 0;
    if (use_atomic) {
        hipMemsetAsync(ws, 0, sizeof(float), stream);
        ssim_kernel<<<grid, 256, 0, stream>>>(x, y, ws, ws, 1, wt);
        finalize_kernel<<<1, 1, 0, stream>>>(ws, out);
    } else {
        float* bsum = ws + NPART;
        ssim_kernel<<<grid, 256, 0, stream>>>(x, y, ws, ws, 0, wt);
        reduce1_kernel<<<NRB, 1024, 0, stream>>>(ws, bsum);
        reduce2_kernel<<<1, 64, 0, stream>>>(bsum, out);
    }
}